// Round 11
// baseline (438.160 us; speedup 1.0000x reference)
//
#include <hip/hip_runtime.h>
#include <cstdint>
#include <cstddef>

typedef __bf16 bf16_t;
typedef bf16_t bf16x8 __attribute__((ext_vector_type(8)));
typedef bf16_t bf16x4v __attribute__((ext_vector_type(4)));
typedef float f32x4 __attribute__((ext_vector_type(4)));

#define NEGV (-1e9f)

#define GLDS(gp, lp) __builtin_amdgcn_global_load_lds( \
    (const __attribute__((address_space(1))) void*)(gp), \
    (__attribute__((address_space(3))) void*)(lp), 16, 0, 0)

// ============================================================ prep mega-kernel
struct PrepArgs {
    const float* w512src[8]; bf16_t* w512dst[8];
    const float* w128src[2]; bf16_t* w128dst[2];
    const float* logicF; const float* physF;
    bf16_t* featsSb; bf16_t* featsPb;
    const int* mask; uint32_t* bits;
    int* cntC; int* cntR; int* cntL; int* firstL; int* dist;
    float* pooled; float* hacc;
};

__global__ __launch_bounds__(256)
void k_prep(PrepArgs p) {
    __shared__ float tb[64][65];
    const int b = blockIdx.x, tid = threadIdx.x;
    if (b < 544) {
        // transpose-convert f32 [K][N] -> bf16 [N][K], 64x64 tiles
        const float* src; bf16_t* dst; int K, tile;
        if (b < 512) { src = p.w512src[b >> 6]; dst = p.w512dst[b >> 6]; K = 512; tile = b & 63; }
        else { int bb = b - 512; src = p.w128src[bb >> 4]; dst = p.w128dst[bb >> 4]; K = 128; tile = bb & 15; }
        const int N = 512;
        int kt = tile >> 3, tc = tile & 7;
        int cx = tid & 63, ry = tid >> 6;
#pragma unroll
        for (int q = 0; q < 16; ++q) {
            int r = q * 4 + ry;
            tb[r][cx] = src[(size_t)(kt * 64 + r) * N + tc * 64 + cx];
        }
        __syncthreads();
#pragma unroll
        for (int q = 0; q < 16; ++q) {
            int r2 = q * 4 + ry;
            dst[(size_t)(tc * 64 + r2) * K + kt * 64 + cx] = (bf16_t)tb[cx][r2];
        }
    } else if (b < 672) {
        size_t e0 = (size_t)(b - 544) * 1024 + tid * 4;
        float4 v = *(const float4*)(p.logicF + e0);
        bf16x4v o; o[0]=(bf16_t)v.x; o[1]=(bf16_t)v.y; o[2]=(bf16_t)v.z; o[3]=(bf16_t)v.w;
        *(bf16x4v*)(p.featsSb + e0) = o;
    } else if (b < 2720) {
        size_t e0 = (size_t)(b - 672) * 1024 + tid * 4;
        float4 v = *(const float4*)(p.physF + e0);
        bf16x4v o; o[0]=(bf16_t)v.x; o[1]=(bf16_t)v.y; o[2]=(bf16_t)v.z; o[3]=(bf16_t)v.w;
        *(bf16x4v*)(p.featsPb + e0) = o;
    } else if (b < 2784) {
        int gid = (b - 2720) * 256 + tid;   // 0..16383
        p.cntC[gid] = 0; p.cntR[gid] = 0; p.firstL[gid] = 0x7fffffff;
        p.dist[gid] = (gid == 0) ? 0 : 16384;
        if (gid < 1024) { p.cntL[gid] = 0; p.pooled[gid] = 0.0f; }
        if (gid < 512) p.hacc[gid] = 0.0f;
    } else {
        // mask bit-pack: 2048 blocks x 256 threads, 32 elems/thread
        size_t w = (size_t)(b - 2784) * 256 + tid;   // word index, 524288 total
        const int4* q4 = (const int4*)(p.mask + w * 32);
        uint32_t bb = 0;
#pragma unroll
        for (int q = 0; q < 8; ++q) {
            int4 v = q4[q];
            bb |= (v.x != 0 ? 1u : 0u) << (q * 4);
            bb |= (v.y != 0 ? 1u : 0u) << (q * 4 + 1);
            bb |= (v.z != 0 ? 1u : 0u) << (q * 4 + 2);
            bb |= (v.w != 0 ? 1u : 0u) << (q * 4 + 3);
        }
        p.bits[w] = bb;
    }
}

// ============================================================ CSR histogram + trajectory (fused)
__global__ void k_hist3(const int* __restrict__ rowP, const int* __restrict__ colP,
                        const int* __restrict__ rowL, const int* __restrict__ colL,
                        int* cntC, int* cntR, int* cntL, int EP, int EL,
                        const int* __restrict__ topo, const int* __restrict__ acts,
                        int* __restrict__ lastArr, int* __restrict__ firstL) {
    int b = blockIdx.x;
    if (b < 1040) {
        int e = b * 256 + threadIdx.x;
        if (e < EP) atomicAdd(&cntC[colP[e]], 1);
        else if (e < 2 * EP) atomicAdd(&cntR[rowP[e - EP]], 1);
        else if (e < 2 * EP + EL) atomicAdd(&cntL[colL[e - 2 * EP]], 1);
    } else {
        int s = (b - 1040) * 256 + threadIdx.x;   // 0..1023
        int last = (s == 0) ? 0 : acts[topo[s - 1]];
        lastArr[s] = last;
        int a = acts[topo[s]];
        if (a != last) atomicMin(&firstL[last], s);
    }
}

__global__ __launch_bounds__(256)
void k_scan3(int* cntC, int* offC, int* curC,
             int* cntR, int* offR, int* curR,
             int* cntL, int* offL, int* curL) {
    __shared__ int ss[256];
    int tid = threadIdx.x;
    const int* cnt; int* off; int* cur; int n;
    if (blockIdx.x == 0)      { cnt = cntC; off = offC; cur = curC; n = 16384; }
    else if (blockIdx.x == 1) { cnt = cntR; off = offR; cur = curR; n = 16384; }
    else                      { cnt = cntL; off = offL; cur = curL; n = 1024; }
    int chunk = n / 256, base = tid * chunk, s = 0;
    for (int i = 0; i < chunk; ++i) s += cnt[base + i];
    ss[tid] = s; __syncthreads();
    for (int d = 1; d < 256; d <<= 1) {
        int v = (tid >= d) ? ss[tid - d] : 0;
        __syncthreads(); ss[tid] += v; __syncthreads();
    }
    int run = (tid == 0) ? 0 : ss[tid - 1];
    for (int i = 0; i < chunk; ++i) { off[base + i] = run; cur[base + i] = run; run += cnt[base + i]; }
    if (tid == 255) off[n] = run;
}

__global__ void k_scatter3(const int* __restrict__ rowP, const int* __restrict__ colP,
                           const int* __restrict__ rowL, const int* __restrict__ colL,
                           int* curC, int* curR, int* curL,
                           int* erowCP, int* ecolRP, int* erowL, int EP, int EL) {
    int e = blockIdx.x * 256 + threadIdx.x;
    if (e < EP) {
        int c = colP[e]; int q = atomicAdd(&curC[c], 1); erowCP[q] = rowP[e];
    } else if (e < 2 * EP) {
        int e2 = e - EP;
        int c = rowP[e2]; int q = atomicAdd(&curR[c], 1); ecolRP[q] = colP[e2];
    } else if (e < 2 * EP + EL) {
        int e3 = e - 2 * EP;
        int c = colL[e3]; int q = atomicAdd(&curL[c], 1); erowL[q] = rowL[e3];
    }
}

// ============================================================ BFS: one level per dispatch, full-GPU wide
__global__ __launch_bounds__(256)
void k_bfs_level(const int* __restrict__ offR, const int* __restrict__ ecol,
                 int* __restrict__ dist, int lev) {
    int j = blockIdx.x * 256 + threadIdx.x;
    if (dist[j] != lev) return;
    int e0 = offR[j], e1 = offR[j + 1];
    for (int e = e0; e < e1; ++e) {
        int v = ecol[e];
        if (dist[v] == 16384) dist[v] = lev + 1;
    }
}

__global__ __launch_bounds__(256)
void k_fmpack(const int* __restrict__ firstL, const int* __restrict__ dist, int* __restrict__ fm) {
    int j = blockIdx.x * 256 + threadIdx.x;
    int fl = firstL[j]; if (fl > 0xFFFF) fl = 0xFFFF;
    fm[j] = (fl << 16) | dist[j];
}

// ============================================================ GEMM (R7-proven: gload_lds, 2-buffer, swizzled)
struct GemmDesc { const bf16_t* A; const bf16_t* B; const bf16_t* Cin; bf16_t* O;
                  int N; int K; float scale; int relu; };
struct GemmPair { GemmDesc d0; GemmDesc d1; int split; };

__global__ __launch_bounds__(256)
void gemm_mfma(GemmPair args) {
    __shared__ bf16_t As[2][128 * 32];
    __shared__ bf16_t Bs[2][128 * 32];
    const int inSet1 = (blockIdx.y >= args.split);
    const GemmDesc g = inSet1 ? args.d1 : args.d0;
    const int my = blockIdx.y - (inSet1 ? args.split : 0);
    const int m0 = my * 128, n0 = blockIdx.x * 128;
    const int tid = threadIdx.x, wave = tid >> 6, lane = tid & 63;
    const int wm = (wave >> 1) * 64, wn = (wave & 1) * 64;
    const int lr = lane & 15, lk = (lane >> 4) * 8;
    const int K = g.K;
    const int srr = wave * 16 + (lane >> 2);
    const int scb = (((lane & 3) ^ ((lane >> 2) & 3)) << 4);   // pre-swizzled global col byte
    const char* Abase = (const char*)g.A + ((size_t)(m0 + srr) * K) * 2 + scb;
    const char* Bbase = (const char*)g.B + ((size_t)(n0 + srr) * K) * 2 + scb;
    const size_t rstep = (size_t)64 * K * 2;
    f32x4 acc[4][4] = {};

    auto stage = [&](int q, int k0) {
        const char* a0 = Abase + (size_t)k0 * 2;
        const char* b0 = Bbase + (size_t)k0 * 2;
        GLDS(a0,         &As[q][(wave * 16) * 32]);
        GLDS(a0 + rstep, &As[q][(64 + wave * 16) * 32]);
        GLDS(b0,         &Bs[q][(wave * 16) * 32]);
        GLDS(b0 + rstep, &Bs[q][(64 + wave * 16) * 32]);
    };

    stage(0, 0);
    asm volatile("s_waitcnt vmcnt(0)" ::: "memory");
    __syncthreads();
    const int nt = K >> 5;
    for (int t = 0; t < nt; ++t) {
        int cur = t & 1;
        if (t + 1 < nt) stage(cur ^ 1, (t + 1) << 5);
        bf16x8 af[4], bff[4];
#pragma unroll
        for (int mi = 0; mi < 4; ++mi) {
            int r = wm + mi * 16 + lr;
            int pb = r * 64 + ((lk * 2) ^ ((r & 3) << 4));
            af[mi] = *(const bf16x8*)((const char*)&As[cur][0] + pb);
        }
#pragma unroll
        for (int ni = 0; ni < 4; ++ni) {
            int r = wn + ni * 16 + lr;
            int pb = r * 64 + ((lk * 2) ^ ((r & 3) << 4));
            bff[ni] = *(const bf16x8*)((const char*)&Bs[cur][0] + pb);
        }
#pragma unroll
        for (int mi = 0; mi < 4; ++mi)
#pragma unroll
            for (int ni = 0; ni < 4; ++ni)
                acc[mi][ni] = __builtin_amdgcn_mfma_f32_16x16x32_bf16(af[mi], bff[ni], acc[mi][ni], 0, 0, 0);
        asm volatile("s_waitcnt vmcnt(0)" ::: "memory");
        __syncthreads();
    }
    const int rb = m0 + wm + (lane >> 4) * 4;
    const int cb = n0 + wn + lr;
#pragma unroll
    for (int mi = 0; mi < 4; ++mi)
#pragma unroll
        for (int ni = 0; ni < 4; ++ni)
#pragma unroll
            for (int r = 0; r < 4; ++r) {
                int row = rb + mi * 16 + r;
                int col = cb + ni * 16;
                size_t idx = (size_t)row * g.N + col;
                float v = acc[mi][ni][r] * g.scale;
                if (g.Cin) v += (float)g.Cin[idx];
                if (g.relu) v = fmaxf(v, 0.0f);
                g.O[idx] = (bf16_t)v;
            }
}

// ============================================================ FUSED chain: 4 row-local GEMM stages + pooling
// 32 rows/block -> 66.5 KB LDS -> 2 blocks/CU (8 waves/CU) for latency hiding.
// h2 = relu(x@W1); t = relu(h2@W2); h = h2 + t@W3; out = (h@W4)*scale; pooled += colmean(h).
struct FusedSide { const bf16_t* X; const bf16_t* W1; const bf16_t* W2; const bf16_t* W3; const bf16_t* W4;
                   bf16_t* OUT; float* pool; float scale; float pinv; };
struct FusedPair { FusedSide s0; FusedSide s1; int split; };

__global__ __launch_bounds__(256, 2)
void k_fused_chain(FusedPair fp) {
    __shared__ bf16_t bufA[32][520];   // x -> t -> out
    __shared__ bf16_t bufB[32][520];   // h2 -> h
    const int tid = threadIdx.x, wave = tid >> 6, lane = tid & 63;
    const int lr = lane & 15, lkq = lane >> 4;
    const int wc = wave * 128;
    const int inS1 = (blockIdx.x >= fp.split);
    const FusedSide sd = inS1 ? fp.s1 : fp.s0;
    const int mb = blockIdx.x - (inS1 ? fp.split : 0);
    const size_t row0 = (size_t)mb * 32;

    // load x tile (coalesced) into bufA
    const bf16_t* Xt = sd.X + row0 * 512;
#pragma unroll
    for (int q = 0; q < 8; ++q) {
        int flat = (q * 256 + tid) * 8;
        bf16x8 v = *(const bf16x8*)(Xt + flat);
        *(bf16x8*)&bufA[flat >> 9][flat & 511] = v;
    }
    __syncthreads();

    // mode: 0 = relu -> dst LDS; 1 = scale -> dst LDS; 2 = residual(+bufB) -> bufB
    auto run_stage = [&](const bf16_t (*src)[520], const bf16_t* WT, bf16_t (*dst)[520], int mode) {
        f32x4 acc[2][8] = {};
        bf16x8 bc[8];
#pragma unroll
        for (int ni = 0; ni < 8; ++ni)
            bc[ni] = *(const bf16x8*)(WT + (size_t)(wc + ni * 16 + lr) * 512 + lkq * 8);
        for (int st = 0; st < 16; ++st) {
            const int kk = st * 32;
            bf16x8 bn[8];
            if (st < 15) {
#pragma unroll
                for (int ni = 0; ni < 8; ++ni)
                    bn[ni] = *(const bf16x8*)(WT + (size_t)(wc + ni * 16 + lr) * 512 + kk + 32 + lkq * 8);
            }
            bf16x8 af[2];
#pragma unroll
            for (int mi = 0; mi < 2; ++mi)
                af[mi] = *(const bf16x8*)&src[mi * 16 + lr][kk + lkq * 8];
#pragma unroll
            for (int mi = 0; mi < 2; ++mi)
#pragma unroll
                for (int ni = 0; ni < 8; ++ni)
                    acc[mi][ni] = __builtin_amdgcn_mfma_f32_16x16x32_bf16(af[mi], bc[ni], acc[mi][ni], 0, 0, 0);
            if (st < 15) {
#pragma unroll
                for (int ni = 0; ni < 8; ++ni) bc[ni] = bn[ni];
            }
        }
#pragma unroll
        for (int mi = 0; mi < 2; ++mi)
#pragma unroll
            for (int ni = 0; ni < 8; ++ni)
#pragma unroll
                for (int r = 0; r < 4; ++r) {
                    int row = mi * 16 + lkq * 4 + r;
                    int col = wc + ni * 16 + lr;
                    float v = acc[mi][ni][r];
                    if (mode == 0) {
                        dst[row][col] = (bf16_t)fmaxf(v, 0.0f);
                    } else if (mode == 1) {
                        dst[row][col] = (bf16_t)(v * sd.scale);
                    } else {
                        v += (float)bufB[row][col];          // each (row,col) owned by this thread
                        bufB[row][col] = (bf16_t)v;
                    }
                }
    };

    run_stage(bufA, sd.W1, bufB, 0);    __syncthreads();   // h2 in bufB
    run_stage(bufB, sd.W2, bufA, 0);    __syncthreads();   // t  in bufA
    run_stage(bufA, sd.W3, nullptr, 2); __syncthreads();   // h  in bufB
    run_stage(bufB, sd.W4, bufA, 1);    __syncthreads();   // out in bufA (scaled)

    // coalesced writeout of out tile
#pragma unroll
    for (int q = 0; q < 8; ++q) {
        int flat = (q * 256 + tid) * 8;
        bf16x8 v = *(const bf16x8*)&bufA[flat >> 9][flat & 511];
        *(bf16x8*)(sd.OUT + row0 * 512 + flat) = v;
    }

    // pooling: column means of h (bufB), read-only
    float s0 = 0.0f, s1 = 0.0f;
    for (int r = 0; r < 32; ++r) {
        s0 += (float)bufB[r][tid];
        s1 += (float)bufB[r][tid + 256];
    }
    atomicAdd(sd.pool + tid, s0 * sd.pinv);
    atomicAdd(sd.pool + tid + 256, s1 * sd.pinv);
}

// ============================================================ SpMM (fused logic+phys)
__global__ __launch_bounds__(256)
void k_spmm2(const bf16_t* __restrict__ HL, const int* __restrict__ offL, const int* __restrict__ erowL, bf16_t* __restrict__ XL,
             const bf16_t* __restrict__ HP, const int* __restrict__ offP, const int* __restrict__ erowP, bf16_t* __restrict__ XP) {
    int b = blockIdx.x;
    const bf16_t* H; const int* off; const int* erow; bf16_t* X; int c;
    int wib = threadIdx.x >> 6, lane = threadIdx.x & 63;
    if (b < 256) { H = HL; off = offL; erow = erowL; X = XL; c = b * 4 + wib; }
    else { b -= 256; H = HP; off = offP; erow = erowP; X = XP; c = b * 4 + wib; }
    int d0 = lane * 8;
    float acc[8] = {0,0,0,0,0,0,0,0};
    int e0 = off[c], e1 = off[c + 1];
    for (int e = e0; e < e1; ++e) {
        int r = erow[e];
        bf16x8 h = *(const bf16x8*)(H + (size_t)r * 512 + d0);
#pragma unroll
        for (int j = 0; j < 8; ++j) acc[j] += (float)h[j];
    }
    bf16x8 own = *(const bf16x8*)(H + (size_t)c * 512 + d0);
    bf16x8 o;
#pragma unroll
    for (int j = 0; j < 8; ++j) o[j] = (bf16_t)((float)own[j] + acc[j]);
    *(bf16x8*)(X + (size_t)c * 512 + d0) = o;
}

// ============================================================ scan (one-pass online softmax)
__global__ __launch_bounds__(256)
void k_scan2(const bf16_t* __restrict__ S, const uint32_t* __restrict__ bits,
             const int* __restrict__ fm, const int* __restrict__ topo,
             const int* __restrict__ acts, const int* __restrict__ lastA,
             float* __restrict__ slogp, float* __restrict__ sent) {
    const int NPn = 16384, cloud = NPn - 1;
    __shared__ float msh[256], zsh[256], wsh[256];
    __shared__ int ash[256];
    const int s = blockIdx.x, tid = threadIdx.x;
    const int i = topo[s], a = acts[i], last = lastA[s];
    const bf16_t* Srow = S + (size_t)i * NPn;
    const uint32_t* brow = bits + (size_t)i * 512;
    const int ml = fm[last] & 0xFFFF;
    const int baseCloud = (brow[511] >> 31) & 1;
    const int lic = (last == cloud);
    if (lic && baseCloud) {
        if (tid == 0) {
            float M = (float)Srow[cloud];
            slogp[s] = (a == cloud) ? 0.0f : (NEGV - M);
            sent[s] = 0.0f;
        }
        return;
    }
    float m = -3.4e38f, Z = 0.0f, W = 0.0f;
    int any = 0;
    if (!lic) {
        for (int c = 0; c < 8; ++c) {
            int j0 = c * 2048 + tid * 8;
            bf16x8 sv = *(const bf16x8*)(Srow + j0);
            uint32_t b8 = (brow[j0 >> 5] >> (j0 & 24)) & 0xFFu;
            int4 f0 = *(const int4*)(fm + j0);
            int4 f1 = *(const int4*)(fm + j0 + 4);
            int fj[8] = {f0.x, f0.y, f0.z, f0.w, f1.x, f1.y, f1.z, f1.w};
#pragma unroll
            for (int q = 0; q < 8; ++q) {
                int j = j0 + q;
                bool alw = ((b8 >> q) & 1) && ((fj[q] & 0xFFFF) >= ml)
                           && (j == last || (((unsigned)fj[q]) >> 16) >= (unsigned)s);
                if (alw) {
                    any = 1;
                    float l = (float)sv[q];
                    if (l > m) {
                        float d = m - l, ce = expf(d);
                        W = ce * (W + d * Z);
                        Z = ce * Z + 1.0f;
                        m = l;
                    } else {
                        float t = l - m, e = expf(t);
                        Z += e; W += t * e;
                    }
                }
            }
        }
    }
    msh[tid] = m; zsh[tid] = Z; wsh[tid] = W; ash[tid] = any;
    __syncthreads();
    for (int st = 128; st > 0; st >>= 1) {
        if (tid < st) {
            float m1 = msh[tid], Z1 = zsh[tid], W1 = wsh[tid];
            float m2 = msh[tid + st], Z2 = zsh[tid + st], W2 = wsh[tid + st];
            float M2 = fmaxf(m1, m2);
            float e1 = expf(m1 - M2), e2 = expf(m2 - M2);
            zsh[tid] = e1 * Z1 + e2 * Z2;
            wsh[tid] = e1 * (W1 + (m1 - M2) * Z1) + e2 * (W2 + (m2 - M2) * Z2);
            msh[tid] = M2;
            ash[tid] |= ash[tid + st];
        }
        __syncthreads();
    }
    if (tid != 0) return;
    if (ash[0]) {
        float M = msh[0], Zt = zsh[0], Wt = wsh[0];
        float logZ = logf(Zt);
        int fa = fm[a];
        bool alwa = ((brow[a >> 5] >> (a & 31)) & 1) && ((fa & 0xFFFF) >= ml)
                    && (a == last || (((unsigned)fa) >> 16) >= (unsigned)s);
        float la = alwa ? (float)Srow[a] : NEGV;
        slogp[s] = la - M - logZ;
        sent[s] = logZ - Wt / Zt;
        return;
    }
    // fallback modes (not hit for this input) — serial on thread 0
    int baseLast = (brow[last >> 5] >> (last & 31)) & 1;
    if (baseLast) { float M = (float)Srow[last]; slogp[s] = (a == last) ? 0.0f : (NEGV - M); sent[s] = 0.0f; return; }
    if (baseCloud) { float M = (float)Srow[cloud]; slogp[s] = (a == cloud) ? 0.0f : (NEGV - M); sent[s] = 0.0f; return; }
    float mm = -3.4e38f, ZZ = 0.0f, WW = 0.0f;
    for (int j = 0; j < NPn; ++j) {
        if ((brow[j >> 5] >> (j & 31)) & 1) {
            float l = (float)Srow[j];
            if (l > mm) { float d = mm - l, ce = expf(d); WW = ce * (WW + d * ZZ); ZZ = ce * ZZ + 1.0f; mm = l; }
            else { float t = l - mm, e = expf(t); ZZ += e; WW += t * e; }
        }
    }
    if (ZZ == 0.0f) { slogp[s] = -logf((float)NPn); sent[s] = logf((float)NPn); return; }
    float logZ = logf(ZZ);
    int ba = (brow[a >> 5] >> (a & 31)) & 1;
    float la = ba ? (float)Srow[a] : NEGV;
    slogp[s] = la - mm - logZ;
    sent[s] = logZ - WW / ZZ;
}

// ============================================================ value head + final
__global__ __launch_bounds__(256)
void k_vpart(const float* __restrict__ pooled, const float* __restrict__ Wc1, float* __restrict__ hacc) {
    __shared__ float pk[128];
    int b = blockIdx.x, tid = threadIdx.x;
    int k0 = b * 128;
    if (tid < 128) pk[tid] = pooled[k0 + tid];
    __syncthreads();
    float a0 = 0, a1 = 0;
    for (int kk = 0; kk < 128; ++kk) {
        float pv = pk[kk];
        const float* wr = Wc1 + (size_t)(k0 + kk) * 512;
        a0 += pv * wr[tid];
        a1 += pv * wr[tid + 256];
    }
    atomicAdd(&hacc[tid], a0);
    atomicAdd(&hacc[tid + 256], a1);
}

__global__ __launch_bounds__(256)
void k_epilogue(const float* __restrict__ slogp, const float* __restrict__ sent,
                const float* __restrict__ hacc, const float* __restrict__ bc1,
                const float* __restrict__ wc2, float* __restrict__ out) {
    __shared__ float s1[256], s2[256], s3[256];
    int tid = threadIdx.x;
    float a = 0, b = 0;
    for (int k = tid; k < 1024; k += 256) { a += slogp[k]; b += sent[k]; }
    float v = fmaxf(hacc[tid] + bc1[tid], 0.0f) * wc2[tid]
            + fmaxf(hacc[tid + 256] + bc1[tid + 256], 0.0f) * wc2[tid + 256];
    s1[tid] = a; s2[tid] = b; s3[tid] = v;
    __syncthreads();
    for (int st = 128; st > 0; st >>= 1) {
        if (tid < st) { s1[tid] += s1[tid + st]; s2[tid] += s2[tid + st]; s3[tid] += s3[tid + st]; }
        __syncthreads();
    }
    if (tid == 0) { out[0] = s1[0]; out[1] = s2[0]; out[2] = s3[0]; }
}

// =======================================================================
extern "C" void kernel_launch(void* const* d_in, const int* in_sizes, int n_in,
                              void* d_out, int out_size, void* d_ws, size_t ws_size,
                              hipStream_t stream) {
    (void)n_in; (void)out_size; (void)ws_size; (void)in_sizes;
    const int MS = 1024, NP = 16384, EL = 4096, EP = 131072, D = 512;

    const int* logicE = (const int*)d_in[0];
    const float* logicF = (const float*)d_in[1];
    const int* physE = (const int*)d_in[2];
    const float* physF = (const float*)d_in[3];
    const int* acts = (const int*)d_in[4];
    const int* mask = (const int*)d_in[5];       // bool -> int32 on device
    const int* topo = (const int*)d_in[6];
    const float* Ws_in = (const float*)d_in[7];
    const float* Ws_out = (const float*)d_in[8];
    const float* Wp_in = (const float*)d_in[9];
    const float* Wp_out = (const float*)d_in[10];
    const float* sA1 = (const float*)d_in[11];
    const float* sA2 = (const float*)d_in[12];
    const float* pA1 = (const float*)d_in[13];
    const float* pA2 = (const float*)d_in[14];
    const float* Wq = (const float*)d_in[15];
    const float* Wk = (const float*)d_in[16];
    const float* Wc1 = (const float*)d_in[17];
    const float* bc1 = (const float*)d_in[18];
    const float* wc2 = (const float*)d_in[19];
    float* out = (float*)d_out;

    char* wsb = (char*)d_ws;
    size_t off = 0;
    auto alloc = [&](size_t bytes) -> void* {
        off = (off + 255) & ~(size_t)255;
        void* p = wsb + off; off += bytes; return p;
    };

    bf16_t* S_bf    = (bf16_t*)alloc((size_t)MS * NP * 2);
    bf16_t* PB0     = (bf16_t*)alloc((size_t)NP * D * 2);
    bf16_t* PB1     = (bf16_t*)alloc((size_t)NP * D * 2);
    bf16_t* PB2     = (bf16_t*)alloc((size_t)NP * D * 2);
    bf16_t* LB0     = (bf16_t*)alloc((size_t)MS * D * 2);
    bf16_t* LB1     = (bf16_t*)alloc((size_t)MS * D * 2);
    bf16_t* LB2     = (bf16_t*)alloc((size_t)MS * D * 2);
    bf16_t* featsSb = (bf16_t*)alloc((size_t)MS * 128 * 2);
    bf16_t* featsPb = (bf16_t*)alloc((size_t)NP * 128 * 2);
    bf16_t* WsinT   = (bf16_t*)alloc(512 * 128 * 2);
    bf16_t* WpinT   = (bf16_t*)alloc(512 * 128 * 2);
    bf16_t* WsoutT  = (bf16_t*)alloc(512 * 512 * 2);
    bf16_t* sA1T    = (bf16_t*)alloc(512 * 512 * 2);
    bf16_t* sA2T    = (bf16_t*)alloc(512 * 512 * 2);
    bf16_t* WqT     = (bf16_t*)alloc(512 * 512 * 2);
    bf16_t* WpoutT  = (bf16_t*)alloc(512 * 512 * 2);
    bf16_t* pA1T    = (bf16_t*)alloc(512 * 512 * 2);
    bf16_t* pA2T    = (bf16_t*)alloc(512 * 512 * 2);
    bf16_t* WkT    = (bf16_t*)alloc(512 * 512 * 2);
    uint32_t* bits = (uint32_t*)alloc((size_t)MS * NP / 8);   // 2 MB
    int* cntC  = (int*)alloc(NP * 4);
    int* offC  = (int*)alloc((NP + 1) * 4);
    int* curC  = (int*)alloc(NP * 4);
    int* cntR  = (int*)alloc(NP * 4);
    int* offR  = (int*)alloc((NP + 1) * 4);
    int* curR  = (int*)alloc(NP * 4);
    int* cntL  = (int*)alloc(MS * 4);
    int* offL  = (int*)alloc((MS + 1) * 4);
    int* curL  = (int*)alloc(MS * 4);
    int* erowCP = (int*)alloc(EP * 4);
    int* ecolRP = (int*)alloc(EP * 4);
    int* erowL  = (int*)alloc(EL * 4);
    int* firstL = (int*)alloc(NP * 4);
    int* lastA  = (int*)alloc(MS * 4);
    int* dist   = (int*)alloc(NP * 4);
    int* fm     = (int*)alloc(NP * 4);
    float* slogp = (float*)alloc(MS * 4);
    float* sentb = (float*)alloc(MS * 4);
    float* pooled = (float*)alloc(1024 * 4);
    float* hacc   = (float*)alloc(512 * 4);

    const int* rowP = physE;  const int* colP = physE + EP;
    const int* rowL = logicE; const int* colL = logicE + EL;

    // 1. prep (transposes + feat converts + mask bit-pack + zero-init)
    {
        PrepArgs p;
        const float* s512[8] = {Ws_out, sA1, sA2, Wq, Wp_out, pA1, pA2, Wk};
        bf16_t* d512[8] = {WsoutT, sA1T, sA2T, WqT, WpoutT, pA1T, pA2T, WkT};
        for (int q = 0; q < 8; ++q) { p.w512src[q] = s512[q]; p.w512dst[q] = d512[q]; }
        p.w128src[0] = Ws_in; p.w128dst[0] = WsinT;
        p.w128src[1] = Wp_in; p.w128dst[1] = WpinT;
        p.logicF = logicF; p.physF = physF; p.featsSb = featsSb; p.featsPb = featsPb;
        p.mask = mask; p.bits = bits;
        p.cntC = cntC; p.cntR = cntR; p.cntL = cntL; p.firstL = firstL; p.dist = dist;
        p.pooled = pooled; p.hacc = hacc;
        hipLaunchKernelGGL(k_prep, dim3(4832), dim3(256), 0, stream, p);
    }
    // 2. CSR histogram + trajectory (fused)
    hipLaunchKernelGGL(k_hist3, dim3(1044), dim3(256), 0, stream,
                       rowP, colP, rowL, colL, cntC, cntR, cntL, EP, EL,
                       topo, acts, lastA, firstL);
    // 3-4. offsets + scatter
    hipLaunchKernelGGL(k_scan3, dim3(3), dim3(256), 0, stream,
                       cntC, offC, curC, cntR, offR, curR, cntL, offL, curL);
    hipLaunchKernelGGL(k_scatter3, dim3((2 * EP + EL) / 256), dim3(256), 0, stream,
                       rowP, colP, rowL, colL, curC, curR, curL, erowCP, ecolRP, erowL, EP, EL);
    // 5. BFS: 16 wide level dispatches (== 16 bounded Bellman-Ford iterations), then fm pack
    for (int lev = 0; lev < 16; ++lev)
        hipLaunchKernelGGL(k_bfs_level, dim3(64), dim3(256), 0, stream, offR, ecolRP, dist, lev);
    hipLaunchKernelGGL(k_fmpack, dim3(64), dim3(256), 0, stream, firstL, dist, fm);

    // 6. h1 = relu(feats @ Win)   (R7-proven 128x128 GEMM)
    {
        GemmPair gp;
        gp.d0 = {featsSb, WsinT, nullptr, LB0, 512, 128, 1.0f, 1};
        gp.d1 = {featsPb, WpinT, nullptr, PB0, 512, 128, 1.0f, 1};
        gp.split = 8;
        hipLaunchKernelGGL(gemm_mfma, dim3(4, 136), dim3(256), 0, stream, gp);
    }
    // 7. x = h1 + agg
    hipLaunchKernelGGL(k_spmm2, dim3(256 + 4096), dim3(256), 0, stream,
                       LB0, offL, erowL, LB1, PB0, offC, erowCP, PB1);
    // 8. FUSED chain: h2/t/h + q/Kp + pooling   (q -> LB0, Kp -> PB0)
    {
        FusedPair fp;
        fp.s0 = {LB1, WsoutT, sA1T, sA2T, WqT, LB0, pooled,       0.044194173824159216f, 1.0f / 1024.0f};
        fp.s1 = {PB1, WpoutT, pA1T, pA2T, WkT, PB0, pooled + 512, 1.0f,                  1.0f / 16384.0f};
        fp.split = 32;
        hipLaunchKernelGGL(k_fused_chain, dim3(544), dim3(256), 0, stream, fp);
    }
    // 9. S = q @ Kp^T
    {
        GemmPair gp;
        gp.d0 = {LB0, PB0, nullptr, S_bf, NP, 512, 1.0f, 0};
        gp.d1 = gp.d0;
        gp.split = 1000;
        hipLaunchKernelGGL(gemm_mfma, dim3(128, 8), dim3(256), 0, stream, gp);
    }
    // 10. scan
    hipLaunchKernelGGL(k_scan2, dim3(MS), dim3(256), 0, stream,
                       S_bf, bits, fm, topo, acts, lastA, slogp, sentb);
    // 11-12. value head + final
    hipLaunchKernelGGL(k_vpart, dim3(8), dim3(256), 0, stream, pooled, Wc1, hacc);
    hipLaunchKernelGGL(k_epilogue, dim3(1), dim3(256), 0, stream, slogp, sentb, hacc, bc1, wc2, out);
}

// Round 12
// 388.097 us; speedup vs baseline: 1.1290x; 1.1290x over previous
//
#include <hip/hip_runtime.h>
#include <cstdint>
#include <cstddef>

typedef __bf16 bf16_t;
typedef bf16_t bf16x8 __attribute__((ext_vector_type(8)));
typedef bf16_t bf16x4v __attribute__((ext_vector_type(4)));
typedef float f32x4 __attribute__((ext_vector_type(4)));

#define NEGV (-1e9f)

#define GLDS(gp, lp) __builtin_amdgcn_global_load_lds( \
    (const __attribute__((address_space(1))) void*)(gp), \
    (__attribute__((address_space(3))) void*)(lp), 16, 0, 0)

// ============================================================ prep mega-kernel
struct PrepArgs {
    const float* w512src[8]; bf16_t* w512dst[8];
    const float* w128src[2]; bf16_t* w128dst[2];
    const float* logicF; const float* physF;
    bf16_t* featsSb; bf16_t* featsPb;
    const int* mask; uint32_t* bits;
    int* cntC; int* cntR; int* cntL; int* firstL; int* dist;
    float* pooled; float* hacc;
};

__global__ __launch_bounds__(256)
void k_prep(PrepArgs p) {
    __shared__ float tb[64][65];
    const int b = blockIdx.x, tid = threadIdx.x;
    if (b < 544) {
        // transpose-convert f32 [K][N] -> bf16 [N][K], 64x64 tiles
        const float* src; bf16_t* dst; int K, tile;
        if (b < 512) { src = p.w512src[b >> 6]; dst = p.w512dst[b >> 6]; K = 512; tile = b & 63; }
        else { int bb = b - 512; src = p.w128src[bb >> 4]; dst = p.w128dst[bb >> 4]; K = 128; tile = bb & 15; }
        const int N = 512;
        int kt = tile >> 3, tc = tile & 7;
        int cx = tid & 63, ry = tid >> 6;
#pragma unroll
        for (int q = 0; q < 16; ++q) {
            int r = q * 4 + ry;
            tb[r][cx] = src[(size_t)(kt * 64 + r) * N + tc * 64 + cx];
        }
        __syncthreads();
#pragma unroll
        for (int q = 0; q < 16; ++q) {
            int r2 = q * 4 + ry;
            dst[(size_t)(tc * 64 + r2) * K + kt * 64 + cx] = (bf16_t)tb[cx][r2];
        }
    } else if (b < 672) {
        size_t e0 = (size_t)(b - 544) * 1024 + tid * 4;
        float4 v = *(const float4*)(p.logicF + e0);
        bf16x4v o; o[0]=(bf16_t)v.x; o[1]=(bf16_t)v.y; o[2]=(bf16_t)v.z; o[3]=(bf16_t)v.w;
        *(bf16x4v*)(p.featsSb + e0) = o;
    } else if (b < 2720) {
        size_t e0 = (size_t)(b - 672) * 1024 + tid * 4;
        float4 v = *(const float4*)(p.physF + e0);
        bf16x4v o; o[0]=(bf16_t)v.x; o[1]=(bf16_t)v.y; o[2]=(bf16_t)v.z; o[3]=(bf16_t)v.w;
        *(bf16x4v*)(p.featsPb + e0) = o;
    } else if (b < 2784) {
        int gid = (b - 2720) * 256 + tid;   // 0..16383
        p.cntC[gid] = 0; p.cntR[gid] = 0; p.firstL[gid] = 0x7fffffff;
        p.dist[gid] = (gid == 0) ? 0 : 16384;
        if (gid < 1024) { p.cntL[gid] = 0; p.pooled[gid] = 0.0f; }
        if (gid < 512) p.hacc[gid] = 0.0f;
    } else {
        // mask bit-pack: 2048 blocks x 256 threads, 32 elems/thread
        size_t w = (size_t)(b - 2784) * 256 + tid;   // word index, 524288 total
        const int4* q4 = (const int4*)(p.mask + w * 32);
        uint32_t bb = 0;
#pragma unroll
        for (int q = 0; q < 8; ++q) {
            int4 v = q4[q];
            bb |= (v.x != 0 ? 1u : 0u) << (q * 4);
            bb |= (v.y != 0 ? 1u : 0u) << (q * 4 + 1);
            bb |= (v.z != 0 ? 1u : 0u) << (q * 4 + 2);
            bb |= (v.w != 0 ? 1u : 0u) << (q * 4 + 3);
        }
        p.bits[w] = bb;
    }
}

// ============================================================ CSR histogram + trajectory (fused)
__global__ void k_hist3(const int* __restrict__ rowP, const int* __restrict__ colP,
                        const int* __restrict__ rowL, const int* __restrict__ colL,
                        int* cntC, int* cntR, int* cntL, int EP, int EL,
                        const int* __restrict__ topo, const int* __restrict__ acts,
                        int* __restrict__ lastArr, int* __restrict__ firstL) {
    int b = blockIdx.x;
    if (b < 1040) {
        int e = b * 256 + threadIdx.x;
        if (e < EP) atomicAdd(&cntC[colP[e]], 1);
        else if (e < 2 * EP) atomicAdd(&cntR[rowP[e - EP]], 1);
        else if (e < 2 * EP + EL) atomicAdd(&cntL[colL[e - 2 * EP]], 1);
    } else {
        int s = (b - 1040) * 256 + threadIdx.x;   // 0..1023
        int last = (s == 0) ? 0 : acts[topo[s - 1]];
        lastArr[s] = last;
        int a = acts[topo[s]];
        if (a != last) atomicMin(&firstL[last], s);
    }
}

__global__ __launch_bounds__(256)
void k_scan3(int* cntC, int* offC, int* curC,
             int* cntR, int* offR, int* curR,
             int* cntL, int* offL, int* curL) {
    __shared__ int ss[256];
    int tid = threadIdx.x;
    const int* cnt; int* off; int* cur; int n;
    if (blockIdx.x == 0)      { cnt = cntC; off = offC; cur = curC; n = 16384; }
    else if (blockIdx.x == 1) { cnt = cntR; off = offR; cur = curR; n = 16384; }
    else                      { cnt = cntL; off = offL; cur = curL; n = 1024; }
    int chunk = n / 256, base = tid * chunk, s = 0;
    for (int i = 0; i < chunk; ++i) s += cnt[base + i];
    ss[tid] = s; __syncthreads();
    for (int d = 1; d < 256; d <<= 1) {
        int v = (tid >= d) ? ss[tid - d] : 0;
        __syncthreads(); ss[tid] += v; __syncthreads();
    }
    int run = (tid == 0) ? 0 : ss[tid - 1];
    for (int i = 0; i < chunk; ++i) { off[base + i] = run; cur[base + i] = run; run += cnt[base + i]; }
    if (tid == 255) off[n] = run;
}

__global__ void k_scatter3(const int* __restrict__ rowP, const int* __restrict__ colP,
                           const int* __restrict__ rowL, const int* __restrict__ colL,
                           int* curC, int* curR, int* curL,
                           int* erowCP, int* ecolRP, int* erowL, int EP, int EL) {
    int e = blockIdx.x * 256 + threadIdx.x;
    if (e < EP) {
        int c = colP[e]; int q = atomicAdd(&curC[c], 1); erowCP[q] = rowP[e];
    } else if (e < 2 * EP) {
        int e2 = e - EP;
        int c = rowP[e2]; int q = atomicAdd(&curR[c], 1); ecolRP[q] = colP[e2];
    } else if (e < 2 * EP + EL) {
        int e3 = e - 2 * EP;
        int c = colL[e3]; int q = atomicAdd(&curL[c], 1); erowL[q] = rowL[e3];
    }
}

// ============================================================ BFS: one level per dispatch, full-GPU wide
__global__ __launch_bounds__(256)
void k_bfs_level(const int* __restrict__ offR, const int* __restrict__ ecol,
                 int* __restrict__ dist, int lev) {
    int j = blockIdx.x * 256 + threadIdx.x;
    if (dist[j] != lev) return;
    int e0 = offR[j], e1 = offR[j + 1];
    for (int e = e0; e < e1; ++e) {
        int v = ecol[e];
        if (dist[v] == 16384) dist[v] = lev + 1;
    }
}

__global__ __launch_bounds__(256)
void k_fmpack(const int* __restrict__ firstL, const int* __restrict__ dist, int* __restrict__ fm) {
    int j = blockIdx.x * 256 + threadIdx.x;
    int fl = firstL[j]; if (fl > 0xFFFF) fl = 0xFFFF;
    fm[j] = (fl << 16) | dist[j];
}

// ============================================================ GEMM (R7 structure + T1 XCD-chunked swizzle)
struct GemmDesc { const bf16_t* A; const bf16_t* B; const bf16_t* Cin; bf16_t* O;
                  int N; int K; float scale; int relu; };
struct GemmPair { GemmDesc d0; GemmDesc d1; int split; };

__global__ __launch_bounds__(256)
void gemm_mfma(GemmPair args) {
    __shared__ bf16_t As[2][128 * 32];
    __shared__ bf16_t Bs[2][128 * 32];
    // T1: chunk-map flat block index so consecutive flat ids (same A-panel, different
    // N-tile) land on the SAME XCD L2. Requires nwg % 8 == 0 (544, 1024: both ok).
    const int nwg = gridDim.x * gridDim.y;
    const int cpx = nwg >> 3;
    const int pfl = blockIdx.y * gridDim.x + blockIdx.x;
    const int vfl = (pfl & 7) * cpx + (pfl >> 3);
    const int vbx = vfl % gridDim.x;
    const int vby = vfl / gridDim.x;
    const int inSet1 = (vby >= args.split);
    const GemmDesc g = inSet1 ? args.d1 : args.d0;
    const int my = vby - (inSet1 ? args.split : 0);
    const int m0 = my * 128, n0 = vbx * 128;
    const int tid = threadIdx.x, wave = tid >> 6, lane = tid & 63;
    const int wm = (wave >> 1) * 64, wn = (wave & 1) * 64;
    const int lr = lane & 15, lk = (lane >> 4) * 8;
    const int K = g.K;
    const int srr = wave * 16 + (lane >> 2);
    const int scb = (((lane & 3) ^ ((lane >> 2) & 3)) << 4);   // pre-swizzled global col byte
    const char* Abase = (const char*)g.A + ((size_t)(m0 + srr) * K) * 2 + scb;
    const char* Bbase = (const char*)g.B + ((size_t)(n0 + srr) * K) * 2 + scb;
    const size_t rstep = (size_t)64 * K * 2;
    f32x4 acc[4][4] = {};

    auto stage = [&](int q, int k0) {
        const char* a0 = Abase + (size_t)k0 * 2;
        const char* b0 = Bbase + (size_t)k0 * 2;
        GLDS(a0,         &As[q][(wave * 16) * 32]);
        GLDS(a0 + rstep, &As[q][(64 + wave * 16) * 32]);
        GLDS(b0,         &Bs[q][(wave * 16) * 32]);
        GLDS(b0 + rstep, &Bs[q][(64 + wave * 16) * 32]);
    };

    stage(0, 0);
    asm volatile("s_waitcnt vmcnt(0)" ::: "memory");
    __syncthreads();
    const int nt = K >> 5;
    for (int t = 0; t < nt; ++t) {
        int cur = t & 1;
        if (t + 1 < nt) stage(cur ^ 1, (t + 1) << 5);
        bf16x8 af[4], bff[4];
#pragma unroll
        for (int mi = 0; mi < 4; ++mi) {
            int r = wm + mi * 16 + lr;
            int pb = r * 64 + ((lk * 2) ^ ((r & 3) << 4));
            af[mi] = *(const bf16x8*)((const char*)&As[cur][0] + pb);
        }
#pragma unroll
        for (int ni = 0; ni < 4; ++ni) {
            int r = wn + ni * 16 + lr;
            int pb = r * 64 + ((lk * 2) ^ ((r & 3) << 4));
            bff[ni] = *(const bf16x8*)((const char*)&Bs[cur][0] + pb);
        }
#pragma unroll
        for (int mi = 0; mi < 4; ++mi)
#pragma unroll
            for (int ni = 0; ni < 4; ++ni)
                acc[mi][ni] = __builtin_amdgcn_mfma_f32_16x16x32_bf16(af[mi], bff[ni], acc[mi][ni], 0, 0, 0);
        asm volatile("s_waitcnt vmcnt(0)" ::: "memory");
        __syncthreads();
    }
    const int rb = m0 + wm + (lane >> 4) * 4;
    const int cb = n0 + wn + lr;
#pragma unroll
    for (int mi = 0; mi < 4; ++mi)
#pragma unroll
        for (int ni = 0; ni < 4; ++ni)
#pragma unroll
            for (int r = 0; r < 4; ++r) {
                int row = rb + mi * 16 + r;
                int col = cb + ni * 16;
                size_t idx = (size_t)row * g.N + col;
                float v = acc[mi][ni][r] * g.scale;
                if (g.Cin) v += (float)g.Cin[idx];
                if (g.relu) v = fmaxf(v, 0.0f);
                g.O[idx] = (bf16_t)v;
            }
}

// ============================================================ SpMM (fused logic+phys)
__global__ __launch_bounds__(256)
void k_spmm2(const bf16_t* __restrict__ HL, const int* __restrict__ offL, const int* __restrict__ erowL, bf16_t* __restrict__ XL,
             const bf16_t* __restrict__ HP, const int* __restrict__ offP, const int* __restrict__ erowP, bf16_t* __restrict__ XP) {
    int b = blockIdx.x;
    const bf16_t* H; const int* off; const int* erow; bf16_t* X; int c;
    int wib = threadIdx.x >> 6, lane = threadIdx.x & 63;
    if (b < 256) { H = HL; off = offL; erow = erowL; X = XL; c = b * 4 + wib; }
    else { b -= 256; H = HP; off = offP; erow = erowP; X = XP; c = b * 4 + wib; }
    int d0 = lane * 8;
    float acc[8] = {0,0,0,0,0,0,0,0};
    int e0 = off[c], e1 = off[c + 1];
    for (int e = e0; e < e1; ++e) {
        int r = erow[e];
        bf16x8 h = *(const bf16x8*)(H + (size_t)r * 512 + d0);
#pragma unroll
        for (int j = 0; j < 8; ++j) acc[j] += (float)h[j];
    }
    bf16x8 own = *(const bf16x8*)(H + (size_t)c * 512 + d0);
    bf16x8 o;
#pragma unroll
    for (int j = 0; j < 8; ++j) o[j] = (bf16_t)((float)own[j] + acc[j]);
    *(bf16x8*)(X + (size_t)c * 512 + d0) = o;
}

// ============================================================ scan (one-pass online softmax)
__global__ __launch_bounds__(256)
void k_scan2(const bf16_t* __restrict__ S, const uint32_t* __restrict__ bits,
             const int* __restrict__ fm, const int* __restrict__ topo,
             const int* __restrict__ acts, const int* __restrict__ lastA,
             float* __restrict__ slogp, float* __restrict__ sent) {
    const int NPn = 16384, cloud = NPn - 1;
    __shared__ float msh[256], zsh[256], wsh[256];
    __shared__ int ash[256];
    const int s = blockIdx.x, tid = threadIdx.x;
    const int i = topo[s], a = acts[i], last = lastA[s];
    const bf16_t* Srow = S + (size_t)i * NPn;
    const uint32_t* brow = bits + (size_t)i * 512;
    const int ml = fm[last] & 0xFFFF;
    const int baseCloud = (brow[511] >> 31) & 1;
    const int lic = (last == cloud);
    if (lic && baseCloud) {
        if (tid == 0) {
            float M = (float)Srow[cloud];
            slogp[s] = (a == cloud) ? 0.0f : (NEGV - M);
            sent[s] = 0.0f;
        }
        return;
    }
    float m = -3.4e38f, Z = 0.0f, W = 0.0f;
    int any = 0;
    if (!lic) {
        for (int c = 0; c < 8; ++c) {
            int j0 = c * 2048 + tid * 8;
            bf16x8 sv = *(const bf16x8*)(Srow + j0);
            uint32_t b8 = (brow[j0 >> 5] >> (j0 & 24)) & 0xFFu;
            int4 f0 = *(const int4*)(fm + j0);
            int4 f1 = *(const int4*)(fm + j0 + 4);
            int fj[8] = {f0.x, f0.y, f0.z, f0.w, f1.x, f1.y, f1.z, f1.w};
#pragma unroll
            for (int q = 0; q < 8; ++q) {
                int j = j0 + q;
                bool alw = ((b8 >> q) & 1) && ((fj[q] & 0xFFFF) >= ml)
                           && (j == last || (((unsigned)fj[q]) >> 16) >= (unsigned)s);
                if (alw) {
                    any = 1;
                    float l = (float)sv[q];
                    if (l > m) {
                        float d = m - l, ce = expf(d);
                        W = ce * (W + d * Z);
                        Z = ce * Z + 1.0f;
                        m = l;
                    } else {
                        float t = l - m, e = expf(t);
                        Z += e; W += t * e;
                    }
                }
            }
        }
    }
    msh[tid] = m; zsh[tid] = Z; wsh[tid] = W; ash[tid] = any;
    __syncthreads();
    for (int st = 128; st > 0; st >>= 1) {
        if (tid < st) {
            float m1 = msh[tid], Z1 = zsh[tid], W1 = wsh[tid];
            float m2 = msh[tid + st], Z2 = zsh[tid + st], W2 = wsh[tid + st];
            float M2 = fmaxf(m1, m2);
            float e1 = expf(m1 - M2), e2 = expf(m2 - M2);
            zsh[tid] = e1 * Z1 + e2 * Z2;
            wsh[tid] = e1 * (W1 + (m1 - M2) * Z1) + e2 * (W2 + (m2 - M2) * Z2);
            msh[tid] = M2;
            ash[tid] |= ash[tid + st];
        }
        __syncthreads();
    }
    if (tid != 0) return;
    if (ash[0]) {
        float M = msh[0], Zt = zsh[0], Wt = wsh[0];
        float logZ = logf(Zt);
        int fa = fm[a];
        bool alwa = ((brow[a >> 5] >> (a & 31)) & 1) && ((fa & 0xFFFF) >= ml)
                    && (a == last || (((unsigned)fa) >> 16) >= (unsigned)s);
        float la = alwa ? (float)Srow[a] : NEGV;
        slogp[s] = la - M - logZ;
        sent[s] = logZ - Wt / Zt;
        return;
    }
    // fallback modes (not hit for this input) — serial on thread 0
    int baseLast = (brow[last >> 5] >> (last & 31)) & 1;
    if (baseLast) { float M = (float)Srow[last]; slogp[s] = (a == last) ? 0.0f : (NEGV - M); sent[s] = 0.0f; return; }
    if (baseCloud) { float M = (float)Srow[cloud]; slogp[s] = (a == cloud) ? 0.0f : (NEGV - M); sent[s] = 0.0f; return; }
    float mm = -3.4e38f, ZZ = 0.0f, WW = 0.0f;
    for (int j = 0; j < NPn; ++j) {
        if ((brow[j >> 5] >> (j & 31)) & 1) {
            float l = (float)Srow[j];
            if (l > mm) { float d = mm - l, ce = expf(d); WW = ce * (WW + d * ZZ); ZZ = ce * ZZ + 1.0f; mm = l; }
            else { float t = l - mm, e = expf(t); ZZ += e; WW += t * e; }
        }
    }
    if (ZZ == 0.0f) { slogp[s] = -logf((float)NPn); sent[s] = logf((float)NPn); return; }
    float logZ = logf(ZZ);
    int ba = (brow[a >> 5] >> (a & 31)) & 1;
    float la = ba ? (float)Srow[a] : NEGV;
    slogp[s] = la - mm - logZ;
    sent[s] = logZ - WW / ZZ;
}

// ============================================================ value head + final
__global__ __launch_bounds__(256)
void k_pool2(const bf16_t* __restrict__ HL, const bf16_t* __restrict__ HP, float* __restrict__ pooled) {
    int b = blockIdx.x, tid = threadIdx.x;
    const bf16_t* H; float* dst; int R, bb, ng; float inv;
    if (b < 16) { H = HL; dst = pooled; R = 1024; inv = 1.0f / 1024.0f; bb = b; ng = 16; }
    else { H = HP; dst = pooled + 512; R = 16384; inv = 1.0f / 16384.0f; bb = b - 16; ng = 128; }
    float a0 = 0, a1 = 0;
    for (int r = bb; r < R; r += ng) {
        a0 += (float)H[(size_t)r * 512 + tid];
        a1 += (float)H[(size_t)r * 512 + tid + 256];
    }
    atomicAdd(&dst[tid], a0 * inv);
    atomicAdd(&dst[tid + 256], a1 * inv);
}

__global__ __launch_bounds__(256)
void k_vpart(const float* __restrict__ pooled, const float* __restrict__ Wc1, float* __restrict__ hacc) {
    __shared__ float pk[128];
    int b = blockIdx.x, tid = threadIdx.x;
    int k0 = b * 128;
    if (tid < 128) pk[tid] = pooled[k0 + tid];
    __syncthreads();
    float a0 = 0, a1 = 0;
    for (int kk = 0; kk < 128; ++kk) {
        float pv = pk[kk];
        const float* wr = Wc1 + (size_t)(k0 + kk) * 512;
        a0 += pv * wr[tid];
        a1 += pv * wr[tid + 256];
    }
    atomicAdd(&hacc[tid], a0);
    atomicAdd(&hacc[tid + 256], a1);
}

__global__ __launch_bounds__(256)
void k_epilogue(const float* __restrict__ slogp, const float* __restrict__ sent,
                const float* __restrict__ hacc, const float* __restrict__ bc1,
                const float* __restrict__ wc2, float* __restrict__ out) {
    __shared__ float s1[256], s2[256], s3[256];
    int tid = threadIdx.x;
    float a = 0, b = 0;
    for (int k = tid; k < 1024; k += 256) { a += slogp[k]; b += sent[k]; }
    float v = fmaxf(hacc[tid] + bc1[tid], 0.0f) * wc2[tid]
            + fmaxf(hacc[tid + 256] + bc1[tid + 256], 0.0f) * wc2[tid + 256];
    s1[tid] = a; s2[tid] = b; s3[tid] = v;
    __syncthreads();
    for (int st = 128; st > 0; st >>= 1) {
        if (tid < st) { s1[tid] += s1[tid + st]; s2[tid] += s2[tid + st]; s3[tid] += s3[tid + st]; }
        __syncthreads();
    }
    if (tid == 0) { out[0] = s1[0]; out[1] = s2[0]; out[2] = s3[0]; }
}

// =======================================================================
extern "C" void kernel_launch(void* const* d_in, const int* in_sizes, int n_in,
                              void* d_out, int out_size, void* d_ws, size_t ws_size,
                              hipStream_t stream) {
    (void)n_in; (void)out_size; (void)ws_size; (void)in_sizes;
    const int MS = 1024, NP = 16384, EL = 4096, EP = 131072, D = 512;

    const int* logicE = (const int*)d_in[0];
    const float* logicF = (const float*)d_in[1];
    const int* physE = (const int*)d_in[2];
    const float* physF = (const float*)d_in[3];
    const int* acts = (const int*)d_in[4];
    const int* mask = (const int*)d_in[5];       // bool -> int32 on device
    const int* topo = (const int*)d_in[6];
    const float* Ws_in = (const float*)d_in[7];
    const float* Ws_out = (const float*)d_in[8];
    const float* Wp_in = (const float*)d_in[9];
    const float* Wp_out = (const float*)d_in[10];
    const float* sA1 = (const float*)d_in[11];
    const float* sA2 = (const float*)d_in[12];
    const float* pA1 = (const float*)d_in[13];
    const float* pA2 = (const float*)d_in[14];
    const float* Wq = (const float*)d_in[15];
    const float* Wk = (const float*)d_in[16];
    const float* Wc1 = (const float*)d_in[17];
    const float* bc1 = (const float*)d_in[18];
    const float* wc2 = (const float*)d_in[19];
    float* out = (float*)d_out;

    char* wsb = (char*)d_ws;
    size_t off = 0;
    auto alloc = [&](size_t bytes) -> void* {
        off = (off + 255) & ~(size_t)255;
        void* p = wsb + off; off += bytes; return p;
    };

    bf16_t* S_bf    = (bf16_t*)alloc((size_t)MS * NP * 2);
    bf16_t* PB0     = (bf16_t*)alloc((size_t)NP * D * 2);
    bf16_t* PB1     = (bf16_t*)alloc((size_t)NP * D * 2);
    bf16_t* PB2     = (bf16_t*)alloc((size_t)NP * D * 2);
    bf16_t* LB0     = (bf16_t*)alloc((size_t)MS * D * 2);
    bf16_t* LB1     = (bf16_t*)alloc((size_t)MS * D * 2);
    bf16_t* LB2     = (bf16_t*)alloc((size_t)MS * D * 2);
    bf16_t* featsSb = (bf16_t*)alloc((size_t)MS * 128 * 2);
    bf16_t* featsPb = (bf16_t*)alloc((size_t)NP * 128 * 2);
    bf16_t* WsinT   = (bf16_t*)alloc(512 * 128 * 2);
    bf16_t* WpinT   = (bf16_t*)alloc(512 * 128 * 2);
    bf16_t* WsoutT  = (bf16_t*)alloc(512 * 512 * 2);
    bf16_t* sA1T    = (bf16_t*)alloc(512 * 512 * 2);
    bf16_t* sA2T    = (bf16_t*)alloc(512 * 512 * 2);
    bf16_t* WqT     = (bf16_t*)alloc(512 * 512 * 2);
    bf16_t* WpoutT  = (bf16_t*)alloc(512 * 512 * 2);
    bf16_t* pA1T    = (bf16_t*)alloc(512 * 512 * 2);
    bf16_t* pA2T    = (bf16_t*)alloc(512 * 512 * 2);
    bf16_t* WkT    = (bf16_t*)alloc(512 * 512 * 2);
    uint32_t* bits = (uint32_t*)alloc((size_t)MS * NP / 8);   // 2 MB
    int* cntC  = (int*)alloc(NP * 4);
    int* offC  = (int*)alloc((NP + 1) * 4);
    int* curC  = (int*)alloc(NP * 4);
    int* cntR  = (int*)alloc(NP * 4);
    int* offR  = (int*)alloc((NP + 1) * 4);
    int* curR  = (int*)alloc(NP * 4);
    int* cntL  = (int*)alloc(MS * 4);
    int* offL  = (int*)alloc((MS + 1) * 4);
    int* curL  = (int*)alloc(MS * 4);
    int* erowCP = (int*)alloc(EP * 4);
    int* ecolRP = (int*)alloc(EP * 4);
    int* erowL  = (int*)alloc(EL * 4);
    int* firstL = (int*)alloc(NP * 4);
    int* lastA  = (int*)alloc(MS * 4);
    int* dist   = (int*)alloc(NP * 4);
    int* fm     = (int*)alloc(NP * 4);
    float* slogp = (float*)alloc(MS * 4);
    float* sentb = (float*)alloc(MS * 4);
    float* pooled = (float*)alloc(1024 * 4);
    float* hacc   = (float*)alloc(512 * 4);

    const int* rowP = physE;  const int* colP = physE + EP;
    const int* rowL = logicE; const int* colL = logicE + EL;

    // 1. prep (transposes + feat converts + mask bit-pack + zero-init)
    {
        PrepArgs p;
        const float* s512[8] = {Ws_out, sA1, sA2, Wq, Wp_out, pA1, pA2, Wk};
        bf16_t* d512[8] = {WsoutT, sA1T, sA2T, WqT, WpoutT, pA1T, pA2T, WkT};
        for (int q = 0; q < 8; ++q) { p.w512src[q] = s512[q]; p.w512dst[q] = d512[q]; }
        p.w128src[0] = Ws_in; p.w128dst[0] = WsinT;
        p.w128src[1] = Wp_in; p.w128dst[1] = WpinT;
        p.logicF = logicF; p.physF = physF; p.featsSb = featsSb; p.featsPb = featsPb;
        p.mask = mask; p.bits = bits;
        p.cntC = cntC; p.cntR = cntR; p.cntL = cntL; p.firstL = firstL; p.dist = dist;
        p.pooled = pooled; p.hacc = hacc;
        hipLaunchKernelGGL(k_prep, dim3(4832), dim3(256), 0, stream, p);
    }
    // 2. CSR histogram + trajectory (fused)
    hipLaunchKernelGGL(k_hist3, dim3(1044), dim3(256), 0, stream,
                       rowP, colP, rowL, colL, cntC, cntR, cntL, EP, EL,
                       topo, acts, lastA, firstL);
    // 3-4. offsets + scatter
    hipLaunchKernelGGL(k_scan3, dim3(3), dim3(256), 0, stream,
                       cntC, offC, curC, cntR, offR, curR, cntL, offL, curL);
    hipLaunchKernelGGL(k_scatter3, dim3((2 * EP + EL) / 256), dim3(256), 0, stream,
                       rowP, colP, rowL, colL, curC, curR, curL, erowCP, ecolRP, erowL, EP, EL);
    // 5. BFS: 16 wide level dispatches (== 16 bounded Bellman-Ford iterations), then fm pack
    for (int lev = 0; lev < 16; ++lev)
        hipLaunchKernelGGL(k_bfs_level, dim3(64), dim3(256), 0, stream, offR, ecolRP, dist, lev);
    hipLaunchKernelGGL(k_fmpack, dim3(64), dim3(256), 0, stream, firstL, dist, fm);

    auto gemm2 = [&](const bf16_t* A0, const bf16_t* B0, const bf16_t* C0, bf16_t* O0, float sc0,
                     const bf16_t* A1, const bf16_t* B1, const bf16_t* C1, bf16_t* O1, float sc1,
                     int K, int relu) {
        GemmPair gp;
        gp.d0 = {A0, B0, C0, O0, 512, K, sc0, relu};
        gp.d1 = {A1, B1, C1, O1, 512, K, sc1, relu};
        gp.split = 8;
        hipLaunchKernelGGL(gemm_mfma, dim3(4, 136), dim3(256), 0, stream, gp);
    };

    // 6. h1 = relu(feats @ Win)
    gemm2(featsSb, WsinT, nullptr, LB0, 1.0f, featsPb, WpinT, nullptr, PB0, 1.0f, 128, 1);
    // 7. x = h1 + agg
    hipLaunchKernelGGL(k_spmm2, dim3(256 + 4096), dim3(256), 0, stream,
                       LB0, offL, erowL, LB1, PB0, offC, erowCP, PB1);
    // 8. h2 = relu(x @ Wout)
    gemm2(LB1, WsoutT, nullptr, LB0, 1.0f, PB1, WpoutT, nullptr, PB0, 1.0f, 512, 1);
    // 9. t = relu(h2 @ A1)
    gemm2(LB0, sA1T, nullptr, LB1, 1.0f, PB0, pA1T, nullptr, PB1, 1.0f, 512, 1);
    // 10. h = h2 + t @ A2
    gemm2(LB1, sA2T, LB0, LB2, 1.0f, PB1, pA2T, PB0, PB2, 1.0f, 512, 0);
    // 11. pooling
    hipLaunchKernelGGL(k_pool2, dim3(144), dim3(256), 0, stream, LB2, PB2, pooled);
    // 12. q = (h_s @ Wq)/sqrt(D);  Kp = h_p @ Wk
    gemm2(LB2, WqT, nullptr, LB1, 0.044194173824159216f, PB2, WkT, nullptr, PB1, 1.0f, 512, 0);
    // 13. S = q @ Kp^T
    {
        GemmPair gp;
        gp.d0 = {LB1, PB1, nullptr, S_bf, NP, 512, 1.0f, 0};
        gp.d1 = gp.d0;
        gp.split = 1000;
        hipLaunchKernelGGL(gemm_mfma, dim3(128, 8), dim3(256), 0, stream, gp);
    }
    // 14. scan
    hipLaunchKernelGGL(k_scan2, dim3(MS), dim3(256), 0, stream,
                       S_bf, bits, fm, topo, acts, lastA, slogp, sentb);
    // 15-16. value head + final
    hipLaunchKernelGGL(k_vpart, dim3(8), dim3(256), 0, stream, pooled, Wc1, hacc);
    hipLaunchKernelGGL(k_epilogue, dim3(1), dim3(256), 0, stream, slogp, sentb, hacc, bc1, wc2, out);
}